// Round 4
// baseline (88.269 us; speedup 1.0000x reference)
//
#include <hip/hip_runtime.h>

// Problem constants: B=8, S=4096, D=1024, A=3, C=2, K=64, MARGIN=5
#define DIM      1024
#define SA       12288      // S*A per batch
#define KSAMP    64
#define PRED_OFF 1          // d_out layout: [loss(1) | predict(98304) | total_idx(1536) | cand(512)]
#define TI_OFF   (1 + 98304)
#define CAND_OFF (1 + 98304 + 1536)
#define NBLK     2048

// Fused kernel. Phase 1 (all 2048 blocks): diff-form projection.
//   ldiff[row][a] = dot(X[row], W[:,2a+1]-W[:,2a]) + (b[2a+1]-b[2a])
//   predict = ldiff>0. f64 accumulation; per-row FP order bit-identical to the
//   passing round-3 kernel (same j-chain, same 16-lane butterfly, same bias add).
// Phase 2 (last block only, via agent-scope counter): per-batch first-64-positives
//   ballot scan (top_k == first 64 positives since forced 2.0 > sigmoid and
//   ~6144 positives >> 64), gather ldiff (agent-scope loads — bypass possibly
//   stale per-XCD L2 copies of the poison fill), margin loss, candidate labels.
// 2048 blocks x 256 thr = 16 rows/block, one row per 16-lane q-group; 8 blocks/CU.
__global__ __launch_bounds__(256, 8)
void k_fused(const float* __restrict__ X, const float* __restrict__ W,
             const float* __restrict__ bias, const int* __restrict__ labels,
             float* __restrict__ outPred, float* __restrict__ ldiff,
             unsigned int* __restrict__ counter, float* __restrict__ outTI,
             float* __restrict__ outCand, float* __restrict__ out0) {
  __shared__ float lds_wd[3 * 1024];
  __shared__ int   s_pos[8][KSAMP];
  __shared__ float s_part[8];
  __shared__ int   s_last;

  for (int d = threadIdx.x; d < 1024; d += 256) {
    const float2 w01 = *reinterpret_cast<const float2*>(W + d * 6);
    const float2 w23 = *reinterpret_cast<const float2*>(W + d * 6 + 2);
    const float2 w45 = *reinterpret_cast<const float2*>(W + d * 6 + 4);
    lds_wd[0 * 1024 + d] = w01.y - w01.x;
    lds_wd[1 * 1024 + d] = w23.y - w23.x;
    lds_wd[2 * 1024 + d] = w45.y - w45.x;
  }
  __syncthreads();

  const int tid  = threadIdx.x;
  const int wave = tid >> 6;
  const int lane = tid & 63;
  const int q    = lane & 15;
  const int p    = lane >> 4;
  const int row  = blockIdx.x * 16 + wave * 4 + p;
  const float* xr = X + (size_t)row * DIM;
  const int qb = q * 4;

  double acc0 = 0.0, acc1 = 0.0, acc2 = 0.0;

#pragma unroll 2
  for (int j = 0; j < 16; ++j) {
    const int d = j * 64 + qb;
    const float4 x4 = *reinterpret_cast<const float4*>(xr + d);
    const float4 w0 = *reinterpret_cast<const float4*>(&lds_wd[d]);
    const float4 w1 = *reinterpret_cast<const float4*>(&lds_wd[1024 + d]);
    const float4 w2 = *reinterpret_cast<const float4*>(&lds_wd[2048 + d]);
    const double x0 = x4.x, x1 = x4.y, x2 = x4.z, x3 = x4.w;
    acc0 += x0 * (double)w0.x + x1 * (double)w0.y + x2 * (double)w0.z + x3 * (double)w0.w;
    acc1 += x0 * (double)w1.x + x1 * (double)w1.y + x2 * (double)w1.z + x3 * (double)w1.w;
    acc2 += x0 * (double)w2.x + x1 * (double)w2.y + x2 * (double)w2.z + x3 * (double)w2.w;
  }

  // butterfly across the 16 q-lanes (bits 0..3); p-groups independent
#pragma unroll
  for (int s = 1; s < 16; s <<= 1) {
    acc0 += __shfl_xor(acc0, s, 64);
    acc1 += __shfl_xor(acc1, s, 64);
    acc2 += __shfl_xor(acc2, s, 64);
  }

  const double bd0 = (double)bias[1] - (double)bias[0];
  const double bd1 = (double)bias[3] - (double)bias[2];
  const double bd2 = (double)bias[5] - (double)bias[4];
  const float f0 = (float)(acc0 + bd0);
  const float f1 = (float)(acc1 + bd1);
  const float f2 = (float)(acc2 + bd2);

  if (q == 0) {
    __hip_atomic_store(&ldiff[(size_t)row * 3 + 0], f0, __ATOMIC_RELAXED, __HIP_MEMORY_SCOPE_AGENT);
    __hip_atomic_store(&ldiff[(size_t)row * 3 + 1], f1, __ATOMIC_RELAXED, __HIP_MEMORY_SCOPE_AGENT);
    __hip_atomic_store(&ldiff[(size_t)row * 3 + 2], f2, __ATOMIC_RELAXED, __HIP_MEMORY_SCOPE_AGENT);
  } else if (q == 4) {
    outPred[(size_t)row * 3 + 0] = (f0 > 0.0f) ? 1.0f : 0.0f;
    outPred[(size_t)row * 3 + 1] = (f1 > 0.0f) ? 1.0f : 0.0f;
    outPred[(size_t)row * 3 + 2] = (f2 > 0.0f) ? 1.0f : 0.0f;
  }

  // ---- last-block-done: the final block performs sampling + loss ----
  __syncthreads();   // drains each thread's stores (vmcnt 0) before the barrier
  if (tid == 0) {
    unsigned int old = __hip_atomic_fetch_add(counter, 1u, __ATOMIC_ACQ_REL,
                                              __HIP_MEMORY_SCOPE_AGENT);
    s_last = (old == NBLK - 1) ? 1 : 0;
  }
  __syncthreads();
  if (!s_last) return;

  // wave w scans batches w and w+4 (first 64 positives each, ballot ranking)
#pragma unroll
  for (int bi = 0; bi < 2; ++bi) {
    const int b = wave + bi * 4;
    int found = 0;
    for (int base = 0; base < SA && found < KSAMP; base += 64) {
      const int lab = labels[b * SA + base + lane];
      const unsigned long long m = __ballot(lab == 1);
      if (lab == 1) {
        const int rank = __popcll(m & ((1ull << lane) - 1ull));
        const int pos = found + rank;
        if (pos < KSAMP) s_pos[b][pos] = base + lane;
      }
      found += __popcll(m);
    }
  }
  __syncthreads();

  float part0 = 0.0f, part1 = 0.0f;
#pragma unroll
  for (int bi = 0; bi < 2; ++bi) {
    const int b = wave + bi * 4;
    const int pos = s_pos[b][lane];
    const int seq = pos / 3;
    const int anc = pos - seq * 3;
    const float ld = __hip_atomic_load(&ldiff[b * SA + pos], __ATOMIC_RELAXED,
                                       __HIP_MEMORY_SCOPE_AGENT);
    const float term = fmaxf(0.0f, 5.0f - ld);   // sampled label is 1 by construction

    const int gk = b * KSAMP + lane;
    outTI[gk * 3 + 0] = (float)b;
    outTI[gk * 3 + 1] = (float)seq;
    outTI[gk * 3 + 2] = (float)anc;
    outCand[gk] = (ld > 0.0f) ? 1.0f : 0.0f;

    float t = term;
#pragma unroll
    for (int s = 1; s < 64; s <<= 1) t += __shfl_xor(t, s, 64);
    if (bi == 0) part0 = t; else part1 = t;
  }
  if (lane == 0) { s_part[wave] = part0; s_part[wave + 4] = part1; }
  __syncthreads();
  if (tid == 0) {
    float tot = 0.0f;
#pragma unroll
    for (int i = 0; i < 8; ++i) tot += s_part[i];
    out0[0] = tot * (1.0f / 1024.0f);   // /512 samples /C=2
  }
}

extern "C" void kernel_launch(void* const* d_in, const int* in_sizes, int n_in,
                              void* d_out, int out_size, void* d_ws, size_t ws_size,
                              hipStream_t stream) {
  const float* X     = (const float*)d_in[0];
  const float* W     = (const float*)d_in[1];
  const float* bias  = (const float*)d_in[2];
  const int*   lab   = (const int*)d_in[3];
  float* out   = (float*)d_out;
  float* ldiff = (float*)d_ws;                          // 32768*3 f32 = 384 KB
  unsigned int* counter = (unsigned int*)((char*)d_ws + 32768 * 3 * sizeof(float));

  hipMemsetAsync(counter, 0, sizeof(unsigned int), stream);
  k_fused<<<NBLK, 256, 0, stream>>>(X, W, bias, lab, out + PRED_OFF, ldiff,
                                    counter, out + TI_OFF, out + CAND_OFF, out);
}

// Round 5
// 31.073 us; speedup vs baseline: 2.8407x; 2.8407x over previous
//
#include <hip/hip_runtime.h>

// Problem constants: B=8, S=4096, D=1024, A=3, C=2, K=64, MARGIN=5
#define DIM      1024
#define SA       12288      // S*A per batch
#define KSAMP    64
#define PRED_OFF 1          // d_out layout: [loss(1) | predict(98304) | total_idx(1536) | cand(512)]
#define TI_OFF   (1 + 98304)
#define CAND_OFF (1 + 98304 + 1536)

// ---------------- K1: diff-form projection ----------------
// ldiff[row][a] = dot(X[row], W[:,2a+1]-W[:,2a]) + (b[2a+1]-b[2a]);
// predict = ldiff>0. f64 accumulation. Per-row FP order bit-identical to the
// passing round-3/4 kernels (same j-chain, same 16-lane butterfly, same bias add).
// ROUND-5 CHANGE vs round 3: 2048 blocks (8 blocks/CU -> 32 waves/CU, 2x TLP),
// one row per 16-lane q-group (3 f64 accs/thread), unroll 4. NO device-scope
// atomics anywhere (round 4's fusion caused a per-block L2 writeback storm:
// 136us with FETCH=2MB on replays — pure cache-op stall).
__global__ __launch_bounds__(256, 8)
void k_gemm_pred(const float* __restrict__ X, const float* __restrict__ W,
                 const float* __restrict__ bias, float* __restrict__ outPred,
                 float* __restrict__ ldiff) {
  __shared__ float lds_wd[3 * 1024];
  for (int d = threadIdx.x; d < 1024; d += 256) {
    const float2 w01 = *reinterpret_cast<const float2*>(W + d * 6);
    const float2 w23 = *reinterpret_cast<const float2*>(W + d * 6 + 2);
    const float2 w45 = *reinterpret_cast<const float2*>(W + d * 6 + 4);
    lds_wd[0 * 1024 + d] = w01.y - w01.x;
    lds_wd[1 * 1024 + d] = w23.y - w23.x;
    lds_wd[2 * 1024 + d] = w45.y - w45.x;
  }
  __syncthreads();

  const int tid  = threadIdx.x;
  const int wave = tid >> 6;
  const int lane = tid & 63;
  const int q    = lane & 15;
  const int p    = lane >> 4;
  const int row  = blockIdx.x * 16 + wave * 4 + p;
  const float* xr = X + (size_t)row * DIM;
  const int qb = q * 4;

  double acc0 = 0.0, acc1 = 0.0, acc2 = 0.0;

#pragma unroll 4
  for (int j = 0; j < 16; ++j) {
    const int d = j * 64 + qb;
    const float4 x4 = *reinterpret_cast<const float4*>(xr + d);
    const float4 w0 = *reinterpret_cast<const float4*>(&lds_wd[d]);
    const float4 w1 = *reinterpret_cast<const float4*>(&lds_wd[1024 + d]);
    const float4 w2 = *reinterpret_cast<const float4*>(&lds_wd[2048 + d]);
    const double x0 = x4.x, x1 = x4.y, x2 = x4.z, x3 = x4.w;
    acc0 += x0 * (double)w0.x + x1 * (double)w0.y + x2 * (double)w0.z + x3 * (double)w0.w;
    acc1 += x0 * (double)w1.x + x1 * (double)w1.y + x2 * (double)w1.z + x3 * (double)w1.w;
    acc2 += x0 * (double)w2.x + x1 * (double)w2.y + x2 * (double)w2.z + x3 * (double)w2.w;
  }

  // butterfly across the 16 q-lanes (bits 0..3); p-groups independent
#pragma unroll
  for (int s = 1; s < 16; s <<= 1) {
    acc0 += __shfl_xor(acc0, s, 64);
    acc1 += __shfl_xor(acc1, s, 64);
    acc2 += __shfl_xor(acc2, s, 64);
  }

  const double bd0 = (double)bias[1] - (double)bias[0];
  const double bd1 = (double)bias[3] - (double)bias[2];
  const double bd2 = (double)bias[5] - (double)bias[4];
  const float f0 = (float)(acc0 + bd0);
  const float f1 = (float)(acc1 + bd1);
  const float f2 = (float)(acc2 + bd2);

  if (q == 0) {
    ldiff[(size_t)row * 3 + 0] = f0;
    ldiff[(size_t)row * 3 + 1] = f1;
    ldiff[(size_t)row * 3 + 2] = f2;
  } else if (q == 4) {
    outPred[(size_t)row * 3 + 0] = (f0 > 0.0f) ? 1.0f : 0.0f;
    outPred[(size_t)row * 3 + 1] = (f1 > 0.0f) ? 1.0f : 0.0f;
    outPred[(size_t)row * 3 + 2] = (f2 > 0.0f) ? 1.0f : 0.0f;
  }
}

// ---------------- K2: scan + gather + loss, single block ----------------
// Positives have forced class-1 score 2.0 (> any sigmoid) and ~6144/batch >> 64,
// so top_k (lowest-index tie-break) == first 64 positives in flat order.
// Wave w owns batch w. ldiff flat index: (w*4096+seq)*3+anc == w*SA + pos.
// candidate = (ldiff>0) — bit-identical to K1's pred. loss = sum(term)/(512*2).
// (Exactly the passing round-3 kernel.)
__global__ __launch_bounds__(512)
void k_sample_final(const int* __restrict__ labels, const float* __restrict__ ldiff,
                    float* __restrict__ outTI, float* __restrict__ outCand,
                    float* __restrict__ out0) {
  __shared__ int   s_pos[8][KSAMP];
  __shared__ float s_part[8];
  const int tid  = threadIdx.x;
  const int w    = tid >> 6;       // batch
  const int lane = tid & 63;

  int found = 0;
  for (int base = 0; base < SA && found < KSAMP; base += 64) {
    const int lab = labels[w * SA + base + lane];
    const unsigned long long m = __ballot(lab == 1);
    if (lab == 1) {
      const int rank = __popcll(m & ((1ull << lane) - 1ull));
      const int pos = found + rank;
      if (pos < KSAMP) s_pos[w][pos] = base + lane;
    }
    found += __popcll(m);
  }
  __syncthreads();

  const int pos = s_pos[w][lane];
  const int seq = pos / 3;
  const int anc = pos - seq * 3;
  const float ld = ldiff[w * SA + pos];
  const float term = fmaxf(0.0f, 5.0f - ld);   // sampled label is 1 by construction

  const int gk = w * KSAMP + lane;
  outTI[gk * 3 + 0] = (float)w;
  outTI[gk * 3 + 1] = (float)seq;
  outTI[gk * 3 + 2] = (float)anc;
  outCand[gk] = (ld > 0.0f) ? 1.0f : 0.0f;

  float t = term;
#pragma unroll
  for (int s = 1; s < 64; s <<= 1) t += __shfl_xor(t, s, 64);
  if (lane == 0) s_part[w] = t;
  __syncthreads();
  if (tid == 0) {
    float tot = 0.0f;
#pragma unroll
    for (int i = 0; i < 8; ++i) tot += s_part[i];
    out0[0] = tot * (1.0f / 1024.0f);   // /512 samples /C=2
  }
}

extern "C" void kernel_launch(void* const* d_in, const int* in_sizes, int n_in,
                              void* d_out, int out_size, void* d_ws, size_t ws_size,
                              hipStream_t stream) {
  const float* X     = (const float*)d_in[0];
  const float* W     = (const float*)d_in[1];
  const float* bias  = (const float*)d_in[2];
  const int*   lab   = (const int*)d_in[3];
  float* out   = (float*)d_out;
  float* ldiff = (float*)d_ws;    // 32768*3 floats = 384 KB

  k_gemm_pred<<<2048, 256, 0, stream>>>(X, W, bias, out + PRED_OFF, ldiff);
  k_sample_final<<<1, 512, 0, stream>>>(lab, ldiff,
                                        out + TI_OFF, out + CAND_OFF, out);
}

// Round 6
// 30.063 us; speedup vs baseline: 2.9361x; 1.0336x over previous
//
#include <hip/hip_runtime.h>

// Problem constants: B=8, S=4096, D=1024, A=3, C=2, K=64, MARGIN=5
#define DIM      1024
#define SA       12288      // S*A per batch
#define KSAMP    64
#define PRED_OFF 1          // d_out layout: [loss(1) | predict(98304) | total_idx(1536) | cand(512)]
#define TI_OFF   (1 + 98304)
#define CAND_OFF (1 + 98304 + 1536)
#define SCAN_BLOCKS 8
#define GEMM_BLOCKS 2048

// ---------------- K1: 8 scan blocks + 2048 diff-form GEMM blocks ----------------
// Scan blocks (blockIdx<8, one per batch): top_k == first 64 positives in flat order
// (forced 2.0 > any sigmoid, ~6144 positives >> 64). Load 256 labels in PARALLEL
// (one per thread — no serial latency chain), 4 wave-ballots -> LDS, rank = mask
// prefix; write sampled positions to ws and total_idx directly. P(<64 positives in
// 256 fair coin flips) ~ 1e-16; deterministic serial fallback handles it anyway.
// GEMM blocks: ldiff[row][a] = dot(X[row], W[:,2a+1]-W[:,2a]) + bias-diff, f64 accum,
// bit-identical FP order to the passing round-3/4/5 kernels; predict = ldiff>0.
__global__ __launch_bounds__(256, 8)
void k_gemm_scan(const float* __restrict__ X, const float* __restrict__ W,
                 const float* __restrict__ bias, const int* __restrict__ labels,
                 float* __restrict__ outPred, float* __restrict__ ldiff,
                 int* __restrict__ wsPos, float* __restrict__ outTI) {
  const int tid = threadIdx.x;

  if (blockIdx.x < SCAN_BLOCKS) {
    // ---------- scan path: batch b ----------
    const int b = blockIdx.x;
    __shared__ unsigned long long s_mask[4];
    const int wave = tid >> 6;
    const int lane = tid & 63;
    const int lab = labels[b * SA + tid];          // 256 labels, all in flight
    const unsigned long long m = __ballot(lab == 1);
    if (lane == 0) s_mask[wave] = m;
    __syncthreads();
    int before = 0;
#pragma unroll
    for (int w2 = 0; w2 < 4; ++w2)
      if (w2 < wave) before += __popcll(s_mask[w2]);
    if (lab == 1) {
      const int rank = before + __popcll(m & ((1ull << lane) - 1ull));
      if (rank < KSAMP) {
        wsPos[b * KSAMP + rank] = tid;
        const int seq = tid / 3, anc = tid - seq * 3;
        const int gk = b * KSAMP + rank;
        outTI[gk * 3 + 0] = (float)b;
        outTI[gk * 3 + 1] = (float)seq;
        outTI[gk * 3 + 2] = (float)anc;
      }
    }
    int totAll = 0;
#pragma unroll
    for (int w2 = 0; w2 < 4; ++w2) totAll += __popcll(s_mask[w2]);
    if (totAll < KSAMP && wave == 0) {             // deterministic fallback (never in practice)
      int found = totAll;
      for (int base = 256; base < SA && found < KSAMP; base += 64) {
        const int lab2 = labels[b * SA + base + lane];
        const unsigned long long m2 = __ballot(lab2 == 1);
        if (lab2 == 1) {
          const int rank = found + __popcll(m2 & ((1ull << lane) - 1ull));
          if (rank < KSAMP) {
            const int pos = base + lane;
            wsPos[b * KSAMP + rank] = pos;
            const int seq = pos / 3, anc = pos - seq * 3;
            const int gk = b * KSAMP + rank;
            outTI[gk * 3 + 0] = (float)b;
            outTI[gk * 3 + 1] = (float)seq;
            outTI[gk * 3 + 2] = (float)anc;
          }
        }
        found += __popcll(m2);
      }
    }
    return;
  }

  // ---------- GEMM path ----------
  __shared__ float lds_wd[3 * 1024];
  for (int d = tid; d < 1024; d += 256) {
    const float2 w01 = *reinterpret_cast<const float2*>(W + d * 6);
    const float2 w23 = *reinterpret_cast<const float2*>(W + d * 6 + 2);
    const float2 w45 = *reinterpret_cast<const float2*>(W + d * 6 + 4);
    lds_wd[0 * 1024 + d] = w01.y - w01.x;
    lds_wd[1 * 1024 + d] = w23.y - w23.x;
    lds_wd[2 * 1024 + d] = w45.y - w45.x;
  }
  __syncthreads();

  const int wave = tid >> 6;
  const int lane = tid & 63;
  const int q    = lane & 15;
  const int p    = lane >> 4;
  const int row  = (blockIdx.x - SCAN_BLOCKS) * 16 + wave * 4 + p;
  const float* xr = X + (size_t)row * DIM;
  const int qb = q * 4;

  double acc0 = 0.0, acc1 = 0.0, acc2 = 0.0;

#pragma unroll 4
  for (int j = 0; j < 16; ++j) {
    const int d = j * 64 + qb;
    const float4 x4 = *reinterpret_cast<const float4*>(xr + d);
    const float4 w0 = *reinterpret_cast<const float4*>(&lds_wd[d]);
    const float4 w1 = *reinterpret_cast<const float4*>(&lds_wd[1024 + d]);
    const float4 w2 = *reinterpret_cast<const float4*>(&lds_wd[2048 + d]);
    const double x0 = x4.x, x1 = x4.y, x2 = x4.z, x3 = x4.w;
    acc0 += x0 * (double)w0.x + x1 * (double)w0.y + x2 * (double)w0.z + x3 * (double)w0.w;
    acc1 += x0 * (double)w1.x + x1 * (double)w1.y + x2 * (double)w1.z + x3 * (double)w1.w;
    acc2 += x0 * (double)w2.x + x1 * (double)w2.y + x2 * (double)w2.z + x3 * (double)w2.w;
  }

#pragma unroll
  for (int s = 1; s < 16; s <<= 1) {
    acc0 += __shfl_xor(acc0, s, 64);
    acc1 += __shfl_xor(acc1, s, 64);
    acc2 += __shfl_xor(acc2, s, 64);
  }

  const double bd0 = (double)bias[1] - (double)bias[0];
  const double bd1 = (double)bias[3] - (double)bias[2];
  const double bd2 = (double)bias[5] - (double)bias[4];
  const float f0 = (float)(acc0 + bd0);
  const float f1 = (float)(acc1 + bd1);
  const float f2 = (float)(acc2 + bd2);

  if (q == 0) {
    ldiff[(size_t)row * 3 + 0] = f0;
    ldiff[(size_t)row * 3 + 1] = f1;
    ldiff[(size_t)row * 3 + 2] = f2;
  } else if (q == 4) {
    outPred[(size_t)row * 3 + 0] = (f0 > 0.0f) ? 1.0f : 0.0f;
    outPred[(size_t)row * 3 + 1] = (f1 > 0.0f) ? 1.0f : 0.0f;
    outPred[(size_t)row * 3 + 2] = (f2 > 0.0f) ? 1.0f : 0.0f;
  }
}

// ---------------- K2: tiny finalize — gather ldiff, cand, loss ----------------
// Positions precomputed by the scan blocks. candidate = (ldiff>0), bit-identical
// to K1's predict. loss = sum(max(0, 5-ldiff)) / (512*2).
__global__ __launch_bounds__(512)
void k_final(const float* __restrict__ ldiff, const int* __restrict__ wsPos,
             float* __restrict__ outCand, float* __restrict__ out0) {
  __shared__ float s_part[8];
  const int tid  = threadIdx.x;
  const int w    = tid >> 6;       // batch
  const int lane = tid & 63;

  const int pos = wsPos[w * KSAMP + lane];
  const float ld = ldiff[w * SA + pos];
  const float term = fmaxf(0.0f, 5.0f - ld);   // sampled label is 1 by construction
  outCand[w * KSAMP + lane] = (ld > 0.0f) ? 1.0f : 0.0f;

  float t = term;
#pragma unroll
  for (int s = 1; s < 64; s <<= 1) t += __shfl_xor(t, s, 64);
  if (lane == 0) s_part[w] = t;
  __syncthreads();
  if (tid == 0) {
    float tot = 0.0f;
#pragma unroll
    for (int i = 0; i < 8; ++i) tot += s_part[i];
    out0[0] = tot * (1.0f / 1024.0f);   // /512 samples /C=2
  }
}

extern "C" void kernel_launch(void* const* d_in, const int* in_sizes, int n_in,
                              void* d_out, int out_size, void* d_ws, size_t ws_size,
                              hipStream_t stream) {
  const float* X     = (const float*)d_in[0];
  const float* W     = (const float*)d_in[1];
  const float* bias  = (const float*)d_in[2];
  const int*   lab   = (const int*)d_in[3];
  float* out   = (float*)d_out;
  float* ldiff = (float*)d_ws;                               // 98304 f32 = 384 KB
  int*   wsPos = (int*)((char*)d_ws + 98304 * sizeof(float)); // 512 ints

  k_gemm_scan<<<GEMM_BLOCKS + SCAN_BLOCKS, 256, 0, stream>>>(
      X, W, bias, lab, out + PRED_OFF, ldiff, wsPos, out + TI_OFF);
  k_final<<<1, 512, 0, stream>>>(ldiff, wsPos, out + CAND_OFF, out);
}